// Round 2
// baseline (1261.824 us; speedup 1.0000x reference)
//
#include <hip/hip_runtime.h>

#define B_ 8
#define C_ 256
#define H_ 96
#define W_ 160
#define TX 8
#define NXG (W_ / TX)   // 20
#define ND 9            // displacements per axis
#define NDISP (ND * ND) // 81
#define NSPLIT 4
#define CPS (C_ / NSPLIT)                  // 64 channels per split
#define NTHREAD_BASE (B_ * H_ * ND * NXG)  // 138240

__global__ __launch_bounds__(256, 4) void corr_split_kernel(
    const float* __restrict__ in1,
    const float* __restrict__ in2,
    float* __restrict__ out)
{
    int tid = blockIdx.x * 256 + threadIdx.x;
    const int split = tid / NTHREAD_BASE;
    int r = tid % NTHREAD_BASE;
    const int xg = r % NXG; r /= NXG;
    const int dy = r % ND;  r /= ND;
    const int y  = r % H_;
    const int b  = r / H_;

    const int x0 = xg * TX;
    const int yp = y + dy - 4;   // shifted row in input2 (PAD=MD=4)
    if (yp < 0 || yp >= H_) return;   // zero contribution; out pre-zeroed

    float acc[ND][TX];
    #pragma unroll
    for (int dx = 0; dx < ND; ++dx)
        #pragma unroll
        for (int j = 0; j < TX; ++j)
            acc[dx][j] = 0.f;

    const int chstride = H_ * W_;
    const int c0 = split * CPS;
    const float* p1 = in1 + (((size_t)(b * C_ + c0)) * H_ + y)  * W_ + x0;
    const float* p2 = in2 + (((size_t)(b * C_ + c0)) * H_ + yp) * W_ + (x0 - 4);
    const bool okL = (x0 - 4) >= 0;     // false only for xg == 0
    const bool okR = (x0 + 12) <= W_;   // false only for xg == NXG-1

    const float4 z4 = make_float4(0.f, 0.f, 0.f, 0.f);

    for (int c = 0; c < CPS; ++c) {
        float4 a0 = *reinterpret_cast<const float4*>(p1);
        float4 a1 = *reinterpret_cast<const float4*>(p1 + 4);
        float4 w0 = okL ? *reinterpret_cast<const float4*>(p2)      : z4;
        float4 w1 =       *reinterpret_cast<const float4*>(p2 + 4);
        float4 w2 =       *reinterpret_cast<const float4*>(p2 + 8);
        float4 w3 = okR ? *reinterpret_cast<const float4*>(p2 + 12) : z4;

        float a[TX] = {a0.x, a0.y, a0.z, a0.w, a1.x, a1.y, a1.z, a1.w};
        float w[16] = {w0.x, w0.y, w0.z, w0.w, w1.x, w1.y, w1.z, w1.w,
                       w2.x, w2.y, w2.z, w2.w, w3.x, w3.y, w3.z, w3.w};

        #pragma unroll
        for (int dx = 0; dx < ND; ++dx)
            #pragma unroll
            for (int j = 0; j < TX; ++j)
                acc[dx][j] += a[j] * w[dx + j];

        p1 += chstride;
        p2 += chstride;
    }

    float* outp = out + (((size_t)(b * NDISP + dy * ND)) * H_ + y) * W_ + x0;
    const float s = 1.0f / (float)C_;  // mean over channels
    #pragma unroll
    for (int dx = 0; dx < ND; ++dx) {
        #pragma unroll
        for (int j = 0; j < TX; ++j) {
            unsafeAtomicAdd(outp + dx * chstride + j, acc[dx][j] * s);
        }
    }
}

extern "C" void kernel_launch(void* const* d_in, const int* in_sizes, int n_in,
                              void* d_out, int out_size, void* d_ws, size_t ws_size,
                              hipStream_t stream) {
    const float* in1 = (const float*)d_in[0];
    const float* in2 = (const float*)d_in[1];
    float* out = (float*)d_out;

    // zero the output (atomic accumulation target); 0x00000000 == 0.0f
    hipMemsetAsync(out, 0, (size_t)out_size * sizeof(float), stream);

    const int total_threads = NTHREAD_BASE * NSPLIT;  // 552960
    const int block = 256;
    const int grid = total_threads / block;           // 2160 exactly
    corr_split_kernel<<<grid, block, 0, stream>>>(in1, in2, out);
}

// Round 3
// 478.134 us; speedup vs baseline: 2.6391x; 2.6391x over previous
//
#include <hip/hip_runtime.h>

#define B_ 8
#define C_ 256
#define H_ 96
#define W_ 160
#define ND 9            // displacements per axis
#define NDISP 81
#define PADL 4
#define CK 4            // channels per LDS chunk
#define NCHUNK (C_ / CK)            // 64
#define ROWF 168                    // padded in2 row: 4 + 160 + 4 floats
#define CFLOATS (W_ + ND * ROWF)    // 160 + 1512 = 1672 floats per channel
#define NTHR 384
#define TX 4
#define NXG (W_ / TX)               // 40
#define NCOMP (ND * NXG)            // 360 compute threads
#define NSLOT (CK * NXG + CK * ND * NXG)  // 160 + 1440 = 1600 float4 slots/chunk

__global__ __launch_bounds__(NTHR, 4) void corr_lds_kernel(
    const float* __restrict__ in1,
    const float* __restrict__ in2,
    float* __restrict__ out)
{
    __shared__ float lds[2][CK][CFLOATS];   // 53504 B

    const int tid = threadIdx.x;
    // XCD swizzle: grid 768 = 8 XCD-chunks of 96; XCD k gets batch b=k
    const int sw = (blockIdx.x & 7) * H_ + (blockIdx.x >> 3);
    const int b = sw / H_;
    const int y = sw % H_;

    // ---- one-time zero: x-pads of all rows; full zero for OOB rows (both bufs)
    for (int i = tid; i < 2 * CK * ND; i += NTHR) {
        const int bf = i / (CK * ND);
        const int c  = (i / ND) % CK;
        const int dy = i % ND;
        float* row = &lds[bf][c][W_ + dy * ROWF];
        const int yp = y + dy - PADL;
        if (yp < 0 || yp >= H_) {
            for (int j = 0; j < ROWF; ++j) row[j] = 0.f;
        } else {
            row[0] = row[1] = row[2] = row[3] = 0.f;
            row[ROWF - 4] = row[ROWF - 3] = row[ROWF - 2] = row[ROWF - 1] = 0.f;
        }
    }

    // ---- per-thread staging slots (static 5-way unroll; rule #20: no dyn idx)
    const int chs = H_ * W_;             // channel stride (floats)
    const float4* src[5];
    int dstoff[5];
    bool valid[5];
    #pragma unroll
    for (int k = 0; k < 5; ++k) {
        const int s = tid + k * NTHR;
        if (s < NSLOT) {
            if (s < CK * NXG) {
                const int c = s / NXG, i = s % NXG;
                src[k] = (const float4*)(in1 + ((size_t)(b * C_ + c) * H_ + y) * W_ + i * 4);
                dstoff[k] = c * CFLOATS + i * 4;
                valid[k] = true;
            } else {
                const int s2 = s - CK * NXG;
                const int c = s2 / (ND * NXG);
                const int r = s2 % (ND * NXG);
                const int dy = r / NXG, i = r % NXG;
                const int yp = y + dy - PADL;
                const bool v = (yp >= 0 && yp < H_);
                src[k] = (const float4*)(in2 + ((size_t)(b * C_ + c) * H_ + (v ? yp : 0)) * W_ + i * 4);
                dstoff[k] = c * CFLOATS + W_ + dy * ROWF + 4 + i * 4;
                valid[k] = v;   // OOB rows stay zero; never restaged
            }
        } else {
            src[k] = (const float4*)in1;
            dstoff[k] = 0;
            valid[k] = false;
        }
    }

    // compute-thread coords
    const int dy_t = tid / NXG;          // 0..8 (tid < NCOMP)
    const int x0   = (tid % NXG) * TX;

    float acc[ND][TX];
    #pragma unroll
    for (int dx = 0; dx < ND; ++dx)
        #pragma unroll
        for (int j = 0; j < TX; ++j) acc[dx][j] = 0.f;

    const float4 z4 = make_float4(0.f, 0.f, 0.f, 0.f);
    float4 rg[5];

    // ---- prologue: stage chunk 0 into buffer 0
    #pragma unroll
    for (int k = 0; k < 5; ++k) rg[k] = valid[k] ? src[k][0] : z4;
    #pragma unroll
    for (int k = 0; k < 5; ++k)
        src[k] = (const float4*)((const float*)src[k] + CK * chs);
    #pragma unroll
    for (int k = 0; k < 5; ++k)
        if (valid[k]) *(float4*)(&lds[0][0][0] + dstoff[k]) = rg[k];
    __syncthreads();

    // ---- main loop over channel chunks, double-buffered, 1 barrier/chunk
    for (int kc = 0; kc < NCHUNK; ++kc) {
        const bool has_next = (kc + 1) < NCHUNK;
        if (has_next) {
            #pragma unroll
            for (int k = 0; k < 5; ++k) rg[k] = valid[k] ? src[k][0] : z4;
            #pragma unroll
            for (int k = 0; k < 5; ++k)
                src[k] = (const float4*)((const float*)src[k] + CK * chs);
        }

        if (tid < NCOMP) {
            const float* base = &lds[kc & 1][0][0];
            #pragma unroll
            for (int c = 0; c < CK; ++c) {
                const float* cb = base + c * CFLOATS;
                const float* row = cb + W_ + dy_t * ROWF;
                float4 a4 = *(const float4*)(cb + x0);
                float4 w0 = *(const float4*)(row + x0);
                float4 w1 = *(const float4*)(row + x0 + 4);
                float4 w2 = *(const float4*)(row + x0 + 8);
                float a[TX] = {a4.x, a4.y, a4.z, a4.w};
                float w[12] = {w0.x, w0.y, w0.z, w0.w,
                               w1.x, w1.y, w1.z, w1.w,
                               w2.x, w2.y, w2.z, w2.w};
                #pragma unroll
                for (int dx = 0; dx < ND; ++dx)
                    #pragma unroll
                    for (int j = 0; j < TX; ++j)
                        acc[dx][j] += a[j] * w[dx + j];
            }
        }

        if (has_next) {
            float* dbase = &lds[(kc + 1) & 1][0][0];
            #pragma unroll
            for (int k = 0; k < 5; ++k)
                if (valid[k]) *(float4*)(dbase + dstoff[k]) = rg[k];
            __syncthreads();
        }
    }

    // ---- epilogue: scaled store
    if (tid < NCOMP) {
        const float s = 1.0f / (float)C_;
        float* outp = out + ((size_t)(b * NDISP + dy_t * ND) * H_ + y) * W_ + x0;
        #pragma unroll
        for (int dx = 0; dx < ND; ++dx) {
            float4 o = make_float4(acc[dx][0] * s, acc[dx][1] * s,
                                   acc[dx][2] * s, acc[dx][3] * s);
            *(float4*)(outp + dx * chs) = o;
        }
    }
}

extern "C" void kernel_launch(void* const* d_in, const int* in_sizes, int n_in,
                              void* d_out, int out_size, void* d_ws, size_t ws_size,
                              hipStream_t stream) {
    const float* in1 = (const float*)d_in[0];
    const float* in2 = (const float*)d_in[1];
    float* out = (float*)d_out;

    const int grid = B_ * H_;   // 768
    corr_lds_kernel<<<grid, NTHR, 0, stream>>>(in1, in2, out);
}